// Round 6
// baseline (10445.304 us; speedup 1.0000x reference)
//
#include <hip/hip_runtime.h>
#include <stdint.h>

// ================= problem constants =================
#define B_SZ   128
#define T_LEN  2048
#define DIN    256
#define NU     512
#define NOUT   64
#define EPS_F  0.01f
#define GAM_F  0.01f
#define KT     32
#define NTILES (T_LEN / KT)
#define NC     2                      // chains per WG (latency-hiding interleave)
#define NQW    11                     // exchange quads per wave slice (32 pairs)
#define NQT    44                     // quads per half-h payload (4 waves)

typedef uint32_t u32;
typedef _Float16 h16;
typedef _Float16 __attribute__((ext_vector_type(2))) h16x2;
typedef _Float16 __attribute__((ext_vector_type(8))) h16x8;
typedef float    __attribute__((ext_vector_type(4))) f32x4;
typedef unsigned int __attribute__((ext_vector_type(4))) u32x4;

typedef const __attribute__((address_space(1))) u32* gas_u32p;
typedef __attribute__((address_space(3))) u32* las_u32p;

// ws layout (u32 units):
//   WS_A     : 131072 u32 (512KB)  A = W - W^T - gamma*I, f16x2, per-(jh,wave) slices
//   WS_WH    : 65536 u32  (256KB)  Vh_w as f16 [512][256]
//   WS_WZ    : 65536 u32  (256KB)  Vz_w as f16 [512][256]
//   WS_EXCHF : 128*2*2*44 uint4    FAST exchange slots (sc0 scope: same-XCD shared L2)
//   WS_EXCHS : 128*2*2*44 uint4    SLOW exchange slots (sc1 scope: L3, any XCD)
#define WS_A     0
#define WS_WH    131072
#define WS_WZ    196608
#define WS_EXCHF 262144
#define EXCH_U32 (B_SZ * 2 * 2 * NQT * 4)
#define WS_EXCHS (WS_EXCHF + EXCH_U32)

__device__ __forceinline__ u32 pack2(float lo, float hi) {
  h16x2 v; v.x = (h16)lo; v.y = (h16)hi;
  return __builtin_bit_cast(u32, v);
}

__device__ __forceinline__ float fdot2(u32 h2, u32 a2, float acc) {
#if __has_builtin(__builtin_amdgcn_fdot2)
  return __builtin_amdgcn_fdot2(__builtin_bit_cast(h16x2, h2),
                                __builtin_bit_cast(h16x2, a2), acc, false);
#else
  h16x2 hh = __builtin_bit_cast(h16x2, h2);
  h16x2 aa = __builtin_bit_cast(h16x2, a2);
  return acc + (float)hh.x * (float)aa.x + (float)hh.y * (float)aa.y;
#endif
}

// ================= prep: pack A + weights to f16, zero exch/out =================
__global__ void antirnn_prep(const float* __restrict__ Vh_w,
                             const float* __restrict__ Vz_w,
                             const float* __restrict__ W,
                             u32* __restrict__ ws,
                             float* __restrict__ out) {
  const int idx = blockIdx.x * blockDim.x + threadIdx.x;
  const int stride = gridDim.x * blockDim.x;

  // A pack. Scan-side flat u32 index U = (jh*4+w)*16384 + c4*4096 + pq*256 + l*4 + e.
  // pp = pq*4+e in [0,64): pp<32 -> own-half row-pair (jh*128 + w*32 + pp),
  //                        pp>=32 -> peer-half row-pair ((1-jh)*128 + w*32 + pp-32).
  // col j = jh*256 + l*4 + c4. Element = pair of rows (2rp, 2rp+1) at col j.
  for (int u = idx; u < 131072; u += stride) {
    int e  = u & 3;
    int l  = (u >> 2) & 63;
    int pq = (u >> 8) & 15;
    int c4 = (u >> 12) & 3;
    int w  = (u >> 14) & 3;
    int jh = (u >> 16) & 1;
    int pp = pq * 4 + e;
    int j  = jh * 256 + l * 4 + c4;
    int rp = (pp < 32) ? (jh * 128 + w * 32 + pp)
                       : ((1 - jh) * 128 + w * 32 + (pp - 32));
    int i0 = 2 * rp, i1 = i0 + 1;
    float lo = W[i0 * NU + j] - W[j * NU + i0] - (i0 == j ? GAM_F : 0.f);
    float hi = W[i1 * NU + j] - W[j * NU + i1] - (i1 == j ? GAM_F : 0.f);
    ws[WS_A + u] = pack2(lo, hi);
  }
  // weight conversion (row-major [512][256] f16, pairs along k)
  for (int u = idx; u < 65536; u += stride) {
    int fl = u * 2;
    ws[WS_WH + u] = pack2(Vh_w[fl], Vh_w[fl + 1]);
    ws[WS_WZ + u] = pack2(Vz_w[fl], Vz_w[fl + 1]);
  }
  // zero BOTH exchange regions (stamp 0 != any consumed step) and output
  for (int u = idx; u < 2 * EXCH_U32; u += stride) ws[WS_EXCHF + u] = 0;
  for (int u = idx; u < B_SZ * NOUT; u += stride) out[u] = 0.f;
}

// ================= scan: 128 WGs x 256 thr; pair (g, g+64) splits A columns; NC chains/WG =================
__global__ __launch_bounds__(256, 1) void antirnn_scan(
    const float* __restrict__ x,
    const float* __restrict__ vh_b, const float* __restrict__ vz_b,
    const float* __restrict__ fc_w, const float* __restrict__ fc_b,
    u32* __restrict__ ws, float* __restrict__ out) {

  __shared__ h16  xs[32 * 256];          // 16KB x-tile (f16, xor-swizzled rows), reused per chain
  __shared__ h16  ph[NC][256 * 36];      // 2x18KB vh proj tile [chain][n_local][36]
  __shared__ h16  pz[NC][256 * 36];      // 2x18KB vz proj tile
  __shared__ float part[NC][4 * 256];    // 2x4KB per-wave partial sums [chain][w][col_local]
  __shared__ u32  hp[NC * 256];          // 2KB  full h per chain as f16x2 pairs
  __shared__ u32x4 stageQ[NC][NQT];      // 1.4KB prefetch staging, per-wave 11-quad slices

  const int tid = threadIdx.x;
  const int w   = tid >> 6;          // wave id
  const int l   = tid & 63;
  const int bid = blockIdx.x;
  const int g   = bid & 63;          // chain-group: chains b0, b0+1
  const int jh  = bid >> 6;          // column half owned: j in [jh*256, jh*256+256)
  const int b0  = g * NC;

  const int ownPB  = jh * 128 + w * 32;        // own-half pair base of this wave's slice
  const int peerPB = (1 - jh) * 128 + w * 32;  // peer-half pair base of this wave's slice

  // ---- load my A slice: 4 cols x (32 own + 32 peer) row-pairs per lane ----
  u32 a[256];
  {
    const uint4* Ap = reinterpret_cast<const uint4*>(ws + WS_A) + (jh * 4 + w) * 4096 + l;
#pragma unroll
    for (int rq = 0; rq < 64; ++rq) {
      uint4 q = Ap[rq * 64];
      int base = (rq >> 4) * 64 + (rq & 15) * 4;
      a[base + 0] = q.x; a[base + 1] = q.y; a[base + 2] = q.z; a[base + 3] = q.w;
    }
  }

  hp[tid] = 0; hp[256 + tid] = 0;    // h(0) = 0 for both chains

  float hreg[NC] = {0.f, 0.f};       // this lane owns local col = tid, per chain
  const h16* Wn_h = reinterpret_cast<const h16*>(ws + WS_WH);
  const h16* Wn_z = reinterpret_cast<const h16*>(ws + WS_WZ);
  uint4* exchF = reinterpret_cast<uint4*>(ws + WS_EXCHF);
  uint4* exchS = reinterpret_cast<uint4*>(ws + WS_EXCHS);

#pragma unroll 1
  for (int tile = 0; tile < NTILES; ++tile) {
    // ---- per chain: stage x tile + proj MFMA ----
#pragma unroll 1
    for (int c = 0; c < NC; ++c) {
      const float* xrow = x + (long)(b0 + c) * T_LEN * DIN;
#pragma unroll
      for (int it = 0; it < 16; ++it) {
        int fp = it * 256 + tid;                    // pair index in [0,4096)
        int s  = fp >> 7, dp = fp & 127;
        float2 v = *reinterpret_cast<const float2*>(xrow + (tile * KT + s) * DIN + dp * 2);
        int byteaddr = (s * 512 + dp * 4) ^ ((s & 7) << 4);
        *reinterpret_cast<u32*>(reinterpret_cast<char*>(xs) + byteaddr) = pack2(v.x, v.y);
      }
      __syncthreads();

      // proj MFMA: [32 steps x 256 own cols]; wave -> n-block w*64
      {
        f32x4 acch[2][4], accz[2][4];
#pragma unroll
        for (int mt = 0; mt < 2; ++mt)
#pragma unroll
          for (int nt = 0; nt < 4; ++nt) {
            acch[mt][nt] = (f32x4){0.f, 0.f, 0.f, 0.f};
            accz[mt][nt] = (f32x4){0.f, 0.f, 0.f, 0.f};
          }
        const int lk = (l >> 4) * 8;
        const int ln = l & 15;
#pragma unroll
        for (int kk = 0; kk < 8; ++kk) {
          h16x8 af[2];
#pragma unroll
          for (int mt = 0; mt < 2; ++mt) {
            int s = mt * 16 + ln;
            int byteaddr = (s * 512 + kk * 64 + (l >> 4) * 16) ^ ((s & 7) << 4);
            af[mt] = *reinterpret_cast<const h16x8*>(reinterpret_cast<const char*>(xs) + byteaddr);
          }
#pragma unroll
          for (int nt = 0; nt < 4; ++nt) {
            int ng = jh * 256 + w * 64 + nt * 16 + ln;
            h16x8 bh = *reinterpret_cast<const h16x8*>(Wn_h + ng * 256 + kk * 32 + lk);
            h16x8 bz = *reinterpret_cast<const h16x8*>(Wn_z + ng * 256 + kk * 32 + lk);
#pragma unroll
            for (int mt = 0; mt < 2; ++mt) {
              acch[mt][nt] = __builtin_amdgcn_mfma_f32_16x16x32_f16(af[mt], bh, acch[mt][nt], 0, 0, 0);
              accz[mt][nt] = __builtin_amdgcn_mfma_f32_16x16x32_f16(af[mt], bz, accz[mt][nt], 0, 0, 0);
            }
          }
        }
#pragma unroll
        for (int nt = 0; nt < 4; ++nt) {
          int n  = w * 64 + nt * 16 + ln;
          float bh_ = vh_b[jh * 256 + n];
          float bz_ = vz_b[jh * 256 + n];
#pragma unroll
          for (int mt = 0; mt < 2; ++mt) {
            int s0 = mt * 16 + (l >> 4) * 4;
            *reinterpret_cast<u32*>(&ph[c][n * 36 + s0])     = pack2(acch[mt][nt].x + bh_, acch[mt][nt].y + bh_);
            *reinterpret_cast<u32*>(&ph[c][n * 36 + s0 + 2]) = pack2(acch[mt][nt].z + bh_, acch[mt][nt].w + bh_);
            *reinterpret_cast<u32*>(&pz[c][n * 36 + s0])     = pack2(accz[mt][nt].x + bz_, accz[mt][nt].y + bz_);
            *reinterpret_cast<u32*>(&pz[c][n * 36 + s0 + 2]) = pack2(accz[mt][nt].z + bz_, accz[mt][nt].w + bz_);
          }
        }
      }
      __syncthreads();
    }

    // ---- 32 sequential steps x NC interleaved chain-phases ----
#pragma unroll 1
    for (int s = 0; s < KT; ++s) {
      const int t = tile * KT + s;
#pragma unroll 1
      for (int c = 0; c < NC; ++c) {
        float acc0 = 0.f, acc1 = 0.f, acc2 = 0.f, acc3 = 0.f;

        // --- own-half sub-dot (32 pairs) ---
        {
          const uint4* hpw = reinterpret_cast<const uint4*>(&hp[c * 256 + ownPB]);
          u32 hq[32];
#pragma unroll
          for (int pq = 0; pq < 8; ++pq) {
            uint4 qq = hpw[pq];
            hq[4 * pq + 0] = qq.x; hq[4 * pq + 1] = qq.y;
            hq[4 * pq + 2] = qq.z; hq[4 * pq + 3] = qq.w;
          }
#pragma unroll
          for (int p = 0; p < 32; ++p) {
            acc0 = fdot2(hq[p], a[p],        acc0);
            acc1 = fdot2(hq[p], a[64 + p],   acc1);
            acc2 = fdot2(hq[p], a[128 + p],  acc2);
            acc3 = fdot2(hq[p], a[192 + p],  acc3);
          }
        }

        // --- consume peer slice for (c,t): counted wait on fast-slot prefetch ---
        if (t > 0 && l < NQW) {
          // outstanding (oldest->newest): prefetch, fast-send, slow-send
          asm volatile("s_waitcnt vmcnt(2)" ::: "memory");
          u32x4 v = *reinterpret_cast<const u32x4*>(&stageQ[c][w * NQW + l]);
          if (v[0] != (u32)t) {                        // stale: dual-scope spin fallback
            const int ei = (((b0 + c) * 2 + (1 - jh)) * 2 + (t & 1)) * NQT + w * NQW + l;
            const uint4* srcF = exchF + ei;
            const uint4* srcS = exchS + ei;
            for (;;) {
              asm volatile("global_load_dwordx4 %0, %1, off sc0\n\ts_waitcnt vmcnt(0)"
                           : "=v"(v) : "v"(srcF) : "memory");
              if (v[0] == (u32)t) break;
              asm volatile("global_load_dwordx4 %0, %1, off sc0 sc1\n\ts_waitcnt vmcnt(0)"
                           : "=v"(v) : "v"(srcS) : "memory");
              if (v[0] == (u32)t) break;
            }
          }
#pragma unroll
          for (int k2 = 0; k2 < 3; ++k2) {
            int pi = 3 * l + k2;
            if (pi < 32) hp[c * 256 + peerPB + pi] = v[1 + k2];  // within-wave slice only
          }
        }

        // --- peer-half sub-dot (32 pairs) ---
        {
          const uint4* hpw = reinterpret_cast<const uint4*>(&hp[c * 256 + peerPB]);
          u32 hq[32];
#pragma unroll
          for (int pq = 0; pq < 8; ++pq) {
            uint4 qq = hpw[pq];
            hq[4 * pq + 0] = qq.x; hq[4 * pq + 1] = qq.y;
            hq[4 * pq + 2] = qq.z; hq[4 * pq + 3] = qq.w;
          }
#pragma unroll
          for (int p = 0; p < 32; ++p) {
            acc0 = fdot2(hq[p], a[32 + p],        acc0);
            acc1 = fdot2(hq[p], a[64 + 32 + p],   acc1);
            acc2 = fdot2(hq[p], a[128 + 32 + p],  acc2);
            acc3 = fdot2(hq[p], a[192 + 32 + p],  acc3);
          }
        }
        {
          f32x4 pv = {acc0, acc1, acc2, acc3};
          *reinterpret_cast<f32x4*>(&part[c][w * 256 + l * 4]) = pv;
        }

        // --- prefetch for NEXT phase (cn,tn) from FAST slots (sc0: shared-L2 scope) ---
        {
          const int cn = 1 - c, tn = t + c;
          if (l < NQW) {
            const uint4* nsrc = exchF + ((((b0 + cn) * 2 + (1 - jh)) * 2 + (tn & 1)) * NQT + w * NQW + l);
            __builtin_amdgcn_global_load_lds((gas_u32p)(const u32*)nsrc,
                                             (las_u32p)(u32*)&stageQ[cn][w * NQW],
                                             16, 0, 0x1 /*sc0*/);
          }
        }

        // --- raw barrier: LDS-only fence (keeps prefetch/sends in flight) ---
        asm volatile("s_waitcnt lgkmcnt(0)" ::: "memory");
        __builtin_amdgcn_s_barrier();
        asm volatile("" ::: "memory");

        // --- epilogue: every lane owns local col = tid ---
        {
          float pre = part[c][tid] + part[c][256 + tid] + part[c][512 + tid] + part[c][768 + tid];
          float uh  = pre + (float)ph[c][tid * 36 + s];
          float uz  = pre + (float)pz[c][tid * 36 + s];
          float uhc = fminf(fmaxf(uh, -20.f), 20.f);
          float e2  = __expf(2.f * uhc);
          float th  = 1.f - 2.f / (e2 + 1.f);
          float sg  = 1.f / (1.f + __expf(-uz));
          hreg[c] += EPS_F * th * sg;
          float other = __shfl_xor(hreg[c], 1, 64);
          if (!(tid & 1)) hp[c * 256 + ownPB + (l >> 1)] = pack2(hreg[c], other);
        }

        // --- send my wave's own-half slice (stamp t+1): fast slot (sc0) + slow slot (sc0 sc1) ---
        if (l < NQW) {
          int p0 = 3 * l;
          u32 v0 = hp[c * 256 + ownPB + p0];
          u32 v1 = (p0 + 1 < 32) ? hp[c * 256 + ownPB + p0 + 1] : 0u;
          u32 v2 = (p0 + 2 < 32) ? hp[c * 256 + ownPB + p0 + 2] : 0u;
          u32x4 qd; qd[0] = (u32)(t + 1); qd[1] = v0; qd[2] = v1; qd[3] = v2;
          const int ei = (((b0 + c) * 2 + jh) * 2 + ((t + 1) & 1)) * NQT + w * NQW + l;
          uint4* dstF = exchF + ei;
          uint4* dstS = exchS + ei;
          asm volatile("global_store_dwordx4 %0, %1, off sc0\n\t"
                       "global_store_dwordx4 %2, %1, off sc0 sc1"
                       :: "v"(dstF), "v"(qd), "v"(dstS) : "memory");
        }
      }
    }
  }

  // ---- final fc per chain: out[b,o] += sum_cc h(cc) * fc_w[o, jh*256+cc] ----
#pragma unroll 1
  for (int c = 0; c < NC; ++c) {
    __syncthreads();
    part[0][tid] = hreg[c];
    __syncthreads();
    if (tid < NOUT) {
      float acc = (jh == 0) ? fc_b[tid] : 0.f;
      const float* fr = fc_w + tid * NU + jh * 256;
#pragma unroll 4
      for (int cc = 0; cc < 256; ++cc) acc += part[0][cc] * fr[cc];
      atomicAdd(out + (b0 + c) * NOUT + tid, acc);
    }
  }
}

// ================= launcher =================
extern "C" void kernel_launch(void* const* d_in, const int* in_sizes, int n_in,
                              void* d_out, int out_size, void* d_ws, size_t ws_size,
                              hipStream_t stream) {
  const float* x    = (const float*)d_in[0];
  const float* Vh_w = (const float*)d_in[1];
  const float* Vh_b = (const float*)d_in[2];
  const float* Vz_w = (const float*)d_in[3];
  const float* Vz_b = (const float*)d_in[4];
  const float* W    = (const float*)d_in[5];
  const float* fc_w = (const float*)d_in[6];
  const float* fc_b = (const float*)d_in[7];
  float* out = (float*)d_out;
  u32*   ws  = (u32*)d_ws;

  antirnn_prep<<<512, 256, 0, stream>>>(Vh_w, Vz_w, W, ws, out);
  antirnn_scan<<<128, 256, 0, stream>>>(x, Vh_b, Vz_b, fc_w, fc_b, ws, out);
}

// Round 7
// 7097.820 us; speedup vs baseline: 1.4716x; 1.4716x over previous
//
#include <hip/hip_runtime.h>
#include <stdint.h>

// ================= problem constants =================
#define B_SZ   128
#define T_LEN  2048
#define DIN    256
#define NU     512
#define NOUT   64
#define EPS_F  0.01f
#define GAM_F  0.01f
#define KT     16
#define NTILES (T_LEN / KT)          // 128

typedef uint32_t u32;
typedef _Float16 h16;
typedef _Float16 __attribute__((ext_vector_type(2))) h16x2;
typedef _Float16 __attribute__((ext_vector_type(8))) h16x8;
typedef float    __attribute__((ext_vector_type(4))) f32x4;

typedef const __attribute__((address_space(1))) u32* gas_u32p;
typedef __attribute__((address_space(3))) u32* las_u32p;

// ws layout (u32 units):
//   WS_A  : 131072 u32 (512KB)  A = W - W^T - gamma*I as MFMA B-frags [w][q=nt*16+kk][lane][4]
//   WS_WH : 65536 u32  (256KB)  Vh_w as MFMA B-frags [w][q2=nt*8+kk][lane][4]
//   WS_WZ : 65536 u32  (256KB)  Vz_w same layout
#define WS_A  0
#define WS_WH 131072
#define WS_WZ 196608

__device__ __forceinline__ u32 pack2(float lo, float hi) {
  h16x2 v; v.x = (h16)lo; v.y = (h16)hi;
  return __builtin_bit_cast(u32, v);
}
__device__ __forceinline__ h16x8 as8(uint4 q) { return __builtin_bit_cast(h16x8, q); }

// ================= prep: pack A + proj weights into MFMA fragment layout =================
__global__ void antirnn_prep(const float* __restrict__ Vh_w,
                             const float* __restrict__ Vz_w,
                             const float* __restrict__ W,
                             u32* __restrict__ ws) {
  const int idx = blockIdx.x * blockDim.x + threadIdx.x;
  const int stride = gridDim.x * blockDim.x;

  // A-frags: u32 idx U = ((w*64 + nt*16 + kk)*64 + l)*4 + e
  // col j = w*64 + nt*16 + (l&15); rows k0 = kk*32 + (l>>4)*8 + 2e, k0+1
  for (int u = idx; u < 131072; u += stride) {
    int e  = u & 3;
    int l  = (u >> 2) & 63;
    int q  = (u >> 8) & 63;
    int w  = (u >> 14) & 7;
    int nt = q >> 4, kk = q & 15;
    int j  = w * 64 + nt * 16 + (l & 15);
    int k0 = kk * 32 + (l >> 4) * 8 + 2 * e;
    int k1 = k0 + 1;
    float lo = W[k0 * NU + j] - W[j * NU + k0] - (k0 == j ? GAM_F : 0.f);
    float hi = W[k1 * NU + j] - W[j * NU + k1] - (k1 == j ? GAM_F : 0.f);
    ws[WS_A + u] = pack2(lo, hi);
  }
  // W-frags: u32 idx U2 = ((w*32 + nt*8 + kk)*64 + l)*4 + e ; unit n, k over DIN
  for (int u = idx; u < 65536; u += stride) {
    int e  = u & 3;
    int l  = (u >> 2) & 63;
    int q2 = (u >> 8) & 31;
    int w  = (u >> 13) & 7;
    int nt = q2 >> 3, kk = q2 & 7;
    int n  = w * 64 + nt * 16 + (l & 15);
    int k0 = kk * 32 + (l >> 4) * 8 + 2 * e;
    ws[WS_WH + u] = pack2(Vh_w[n * DIN + k0], Vh_w[n * DIN + k0 + 1]);
    ws[WS_WZ + u] = pack2(Vz_w[n * DIN + k0], Vz_w[n * DIN + k0 + 1]);
  }
}

// ================= scan: 128 WGs x 512 thr; one WG owns one chain, zero cross-CU =================
__global__ __launch_bounds__(512, 2) void antirnn_scan(
    const float* __restrict__ x,
    const float* __restrict__ vh_b, const float* __restrict__ vz_b,
    const float* __restrict__ fc_w, const float* __restrict__ fc_b,
    const u32* __restrict__ ws, float* __restrict__ out) {

  __shared__ u32 ldsA[15 * 8 * 64 * 4];   // 120KB: LDS-resident A-frags [w][slot][lane][4]
  __shared__ u32 phz[2 * 8 * 512];        // 32KB: proj tile [arr][spair][col] (2 steps/u32)
  __shared__ u32 hp[2][256];              // 2KB: h as f16x2 pairs, double-buffered by t&1

  const int tid = threadIdx.x;
  const int w   = tid >> 6;               // wave id: cols [64w, 64w+64)
  const int l   = tid & 63;
  const int lg  = l >> 4;                 // k-slice group
  const int ln  = l & 15;
  const int col = tid;                    // owned output column
  const int b   = blockIdx.x;             // chain

  // ---- A-frags: 49 in regs (nt0: kk0-12; nt1-3: kk0-11), 15 in LDS ----
  uint4 areg[49];
  const uint4* wsA4 = reinterpret_cast<const uint4*>(ws + WS_A);
#pragma unroll
  for (int nt = 0; nt < 4; ++nt)
#pragma unroll
    for (int kk = 0; kk < 16; ++kk) {
      const int RC = (nt == 0) ? 13 : 12;
      if (kk < RC) {
        const int slot = (nt == 0) ? kk : 13 + (nt - 1) * 12 + kk;
        areg[slot] = wsA4[(w * 64 + nt * 16 + kk) * 64 + l];
      }
    }
#pragma unroll
  for (int nt = 0; nt < 4; ++nt)
#pragma unroll
    for (int kk = 0; kk < 16; ++kk) {
      const int RC = (nt == 0) ? 13 : 12;
      if (kk >= RC) {
        const int ls = (nt == 0) ? (kk - 13) : 3 + (nt - 1) * 4 + (kk - 12);
        const u32* src = ws + WS_A + ((w * 64 + nt * 16 + kk) * 64 + l) * 4;
        __builtin_amdgcn_global_load_lds((gas_u32p)src,
                                         (las_u32p)&ldsA[(w * 15 + ls) * 256], 16, 0, 0);
      }
    }

  if (tid < 256) { hp[0][tid] = 0; hp[1][tid] = 0; }
  const float bh = vh_b[col], bz = vz_b[col];
  float hval = 0.f;

  const uint4* wsWH4 = reinterpret_cast<const uint4*>(ws + WS_WH);
  const uint4* wsWZ4 = reinterpret_cast<const uint4*>(ws + WS_WZ);
  const float* xb = x + (long)b * T_LEN * DIN;
  u32 stash[16];

  asm volatile("s_waitcnt vmcnt(0)" ::: "memory");
  __syncthreads();

  // ---- prologue: proj for tile 0 -> phz ----
#pragma unroll
  for (int p = 0; p < 4; ++p) {
    const uint4* wsW = (p >> 1) ? wsWZ4 : wsWH4;
    const int ntA = (p & 1) * 2, ntB = ntA + 1;
    f32x4 pacc0 = {0.f, 0.f, 0.f, 0.f}, pacc1 = {0.f, 0.f, 0.f, 0.f};
#pragma unroll 1
    for (int kkp = 0; kkp < 8; ++kkp) {
      const float* xr = xb + (long)ln * DIN + kkp * 32 + lg * 8;
      float4 x0 = *reinterpret_cast<const float4*>(xr);
      float4 x1 = *reinterpret_cast<const float4*>(xr + 4);
      h16x8 xf;
      xf[0]=(h16)x0.x; xf[1]=(h16)x0.y; xf[2]=(h16)x0.z; xf[3]=(h16)x0.w;
      xf[4]=(h16)x1.x; xf[5]=(h16)x1.y; xf[6]=(h16)x1.z; xf[7]=(h16)x1.w;
      h16x8 wf0 = as8(wsW[(w * 32 + ntA * 8 + kkp) * 64 + l]);
      h16x8 wf1 = as8(wsW[(w * 32 + ntB * 8 + kkp) * 64 + l]);
      pacc0 = __builtin_amdgcn_mfma_f32_16x16x32_f16(xf, wf0, pacc0, 0, 0, 0);
      pacc1 = __builtin_amdgcn_mfma_f32_16x16x32_f16(xf, wf1, pacc1, 0, 0, 0);
    }
    stash[p*4+0] = pack2(pacc0.x, pacc0.y); stash[p*4+1] = pack2(pacc0.z, pacc0.w);
    stash[p*4+2] = pack2(pacc1.x, pacc1.y); stash[p*4+3] = pack2(pacc1.z, pacc1.w);
  }
#pragma unroll
  for (int p = 0; p < 4; ++p) {
    const int arr = p >> 1;
#pragma unroll
    for (int ntx = 0; ntx < 2; ++ntx) {
      const int nt = (p & 1) * 2 + ntx;
      const int cb = w * 64 + nt * 16 + ln;
      phz[(arr * 8 + lg * 2 + 0) * 512 + cb] = stash[p*4 + ntx*2 + 0];
      phz[(arr * 8 + lg * 2 + 1) * 512 + cb] = stash[p*4 + ntx*2 + 1];
    }
  }
  __syncthreads();

  // ---- main loop: 128 tiles x 16 steps ----
#pragma unroll 1
  for (int tile = 0; tile < NTILES; ++tile) {
    const int tsrc = (tile + 1) & (NTILES - 1);           // proj source tile (wraps; last unused)
    const float* xtb = xb + (long)tsrc * KT * DIN;

#pragma unroll
    for (int p = 0; p < 4; ++p) {
      const uint4* wsW = (p >> 1) ? wsWZ4 : wsWH4;
      const int ntA = (p & 1) * 2, ntB = ntA + 1;
      f32x4 pacc0 = {0.f, 0.f, 0.f, 0.f}, pacc1 = {0.f, 0.f, 0.f, 0.f};

#pragma unroll 1
      for (int sp = 0; sp < 4; ++sp) {
        // --- proj for next tile: 2 kk-slices per step (4 MFMA) ---
#pragma unroll
        for (int kh = 0; kh < 2; ++kh) {
          const int kkp = sp * 2 + kh;
          const float* xr = xtb + (long)ln * DIN + kkp * 32 + lg * 8;
          float4 x0 = *reinterpret_cast<const float4*>(xr);
          float4 x1 = *reinterpret_cast<const float4*>(xr + 4);
          h16x8 xf;
          xf[0]=(h16)x0.x; xf[1]=(h16)x0.y; xf[2]=(h16)x0.z; xf[3]=(h16)x0.w;
          xf[4]=(h16)x1.x; xf[5]=(h16)x1.y; xf[6]=(h16)x1.z; xf[7]=(h16)x1.w;
          h16x8 wf0 = as8(wsW[(w * 32 + ntA * 8 + kkp) * 64 + l]);
          h16x8 wf1 = as8(wsW[(w * 32 + ntB * 8 + kkp) * 64 + l]);
          pacc0 = __builtin_amdgcn_mfma_f32_16x16x32_f16(xf, wf0, pacc0, 0, 0, 0);
          pacc1 = __builtin_amdgcn_mfma_f32_16x16x32_f16(xf, wf1, pacc1, 0, 0, 0);
        }

        // --- recurrence: u = h @ A for this wave's 64 cols (64 MFMA) ---
        const u32* hpc = hp[sp & 1];
        u32* hpn = hp[1 - (sp & 1)];
        f32x4 a0 = {0.f,0.f,0.f,0.f}, a1 = a0, a2 = a0, a3 = a0;
#pragma unroll
        for (int kk = 0; kk < 16; ++kk) {
          h16x8 hf = *reinterpret_cast<const h16x8*>(hpc + kk * 16 + lg * 4);
          h16x8 b0, b1, b2, b3;
          if (kk < 13) b0 = as8(areg[kk]);
          else         b0 = *reinterpret_cast<const h16x8*>(&ldsA[(w*15 + (kk-13)) * 256 + l * 4]);
          if (kk < 12) b1 = as8(areg[13 + kk]);
          else         b1 = *reinterpret_cast<const h16x8*>(&ldsA[(w*15 + 3 + (kk-12)) * 256 + l * 4]);
          if (kk < 12) b2 = as8(areg[25 + kk]);
          else         b2 = *reinterpret_cast<const h16x8*>(&ldsA[(w*15 + 7 + (kk-12)) * 256 + l * 4]);
          if (kk < 12) b3 = as8(areg[37 + kk]);
          else         b3 = *reinterpret_cast<const h16x8*>(&ldsA[(w*15 + 11 + (kk-12)) * 256 + l * 4]);
          a0 = __builtin_amdgcn_mfma_f32_16x16x32_f16(hf, b0, a0, 0, 0, 0);
          a1 = __builtin_amdgcn_mfma_f32_16x16x32_f16(hf, b1, a1, 0, 0, 0);
          a2 = __builtin_amdgcn_mfma_f32_16x16x32_f16(hf, b2, a2, 0, 0, 0);
          a3 = __builtin_amdgcn_mfma_f32_16x16x32_f16(hf, b3, a3, 0, 0, 0);
        }

        // --- epilogue: all D rows equal => own col's value is acc[lg].x ---
        {
          const int s2 = p * 2 + (sp >> 1);
          float pre = (lg == 0) ? a0.x : (lg == 1) ? a1.x : (lg == 2) ? a2.x : a3.x;
          h16x2 ph2 = __builtin_bit_cast(h16x2, phz[s2 * 512 + col]);
          h16x2 pz2 = __builtin_bit_cast(h16x2, phz[(8 + s2) * 512 + col]);
          float vh = (float)ph2[sp & 1];
          float vz = (float)pz2[sp & 1];
          float uh = pre + vh + bh;
          float uz = pre + vz + bz;
          float uhc = fminf(fmaxf(uh, -20.f), 20.f);
          float e2  = __expf(2.f * uhc);
          float th  = 1.f - 2.f / (e2 + 1.f);
          float sg  = 1.f / (1.f + __expf(-uz));
          hval += EPS_F * th * sg;
          float oth = __shfl_xor(hval, 1, 64);
          if (!(col & 1)) hpn[col >> 1] = pack2(hval, oth);
        }
        __syncthreads();
      } // sp

      stash[p*4+0] = pack2(pacc0.x, pacc0.y); stash[p*4+1] = pack2(pacc0.z, pacc0.w);
      stash[p*4+2] = pack2(pacc1.x, pacc1.y); stash[p*4+3] = pack2(pacc1.z, pacc1.w);
    } // p

    // --- dump next tile's proj (same-wave cols only: ordered by DS program order) ---
#pragma unroll
    for (int p = 0; p < 4; ++p) {
      const int arr = p >> 1;
#pragma unroll
      for (int ntx = 0; ntx < 2; ++ntx) {
        const int nt = (p & 1) * 2 + ntx;
        const int cb = w * 64 + nt * 16 + ln;
        phz[(arr * 8 + lg * 2 + 0) * 512 + cb] = stash[p*4 + ntx*2 + 0];
        phz[(arr * 8 + lg * 2 + 1) * 512 + cb] = stash[p*4 + ntx*2 + 1];
      }
    }
  } // tile

  // ---- final fc: out[b][o] = fc_b[o] + sum_c h[c] * fc_w[o][c] ----
  __syncthreads();
  float* hbuf = reinterpret_cast<float*>(phz);
  hbuf[col] = hval;
  __syncthreads();
  if (tid < NOUT) {
    float acc = fc_b[tid];
    const float* fr = fc_w + tid * NU;
#pragma unroll 4
    for (int c = 0; c < NU; ++c) acc += hbuf[c] * fr[c];
    out[b * NOUT + tid] = acc;
  }
}

// ================= launcher =================
extern "C" void kernel_launch(void* const* d_in, const int* in_sizes, int n_in,
                              void* d_out, int out_size, void* d_ws, size_t ws_size,
                              hipStream_t stream) {
  const float* x    = (const float*)d_in[0];
  const float* Vh_w = (const float*)d_in[1];
  const float* Vh_b = (const float*)d_in[2];
  const float* Vz_w = (const float*)d_in[3];
  const float* Vz_b = (const float*)d_in[4];
  const float* W    = (const float*)d_in[5];
  const float* fc_w = (const float*)d_in[6];
  const float* fc_b = (const float*)d_in[7];
  float* out = (float*)d_out;
  u32*   ws  = (u32*)d_ws;

  antirnn_prep<<<512, 256, 0, stream>>>(Vh_w, Vz_w, W, ws);
  antirnn_scan<<<128, 512, 0, stream>>>(x, Vh_b, Vz_b, fc_w, fc_b, ws, out);
}